// Round 10
// baseline (426.192 us; speedup 1.0000x reference)
//
#include <hip/hip_runtime.h>
#include <hip/hip_bf16.h>

#define N_NODES 100000
#define N_EDGES 800000
#define N_GRAPHS 16
#define NFEAT 128
#define NHID 128
#define NCLASS 2

#define SCAN_CHUNK 2048
#define NCHUNK ((N_NODES + SCAN_CHUNK - 1) / SCAN_CHUNK)  // 49

#define GEMM_BLOCKS 512
#define N_CHUNKS (N_NODES / 16)  // 6250 exact

#define DEG_BINS 8
#define DEG_SLICES 32
#define DEG_BIN_W (N_NODES / DEG_BINS)          // 12500
#define DEG_SLICE_E (N_EDGES / DEG_SLICES)      // 25000

#define POOL_BLOCKS 512
#define POOL_TPB 1024
#define POOL_WPB (POOL_TPB / 64)                // 16 waves/block

typedef unsigned int uint32;
typedef __attribute__((ext_vector_type(8))) short short8;
typedef __attribute__((ext_vector_type(4))) float f32x4;
typedef __attribute__((ext_vector_type(2))) float f32x2;

// ---- bf16 helpers ----
__device__ __forceinline__ unsigned short f2bf(float f) {
  unsigned u = __float_as_uint(f);
  unsigned r = (u + 0x7fffu + ((u >> 16) & 1u)) >> 16;
  return (unsigned short)r;
}

// ---- fp8 pack helper: 8 floats -> uint2 ----
__device__ __forceinline__ uint2 fp8pack8(const float* o) {
  uint2 u;
  int p = __builtin_amdgcn_cvt_pk_fp8_f32(o[0], o[1], 0, false);
  u.x = (uint32)__builtin_amdgcn_cvt_pk_fp8_f32(o[2], o[3], p, true);
  p = __builtin_amdgcn_cvt_pk_fp8_f32(o[4], o[5], 0, false);
  u.y = (uint32)__builtin_amdgcn_cvt_pk_fp8_f32(o[6], o[7], p, true);
  return u;
}

// -------- k_deg: LDS-privatized per-(bin,slice) histogram, no global atomics --------
// dpart layout TRANSPOSED: dpart[node][32] -> scan reads 128B/node contiguous;
// writes of column s share lines only among same-bin (= same-XCD) blocks.
__global__ __launch_bounds__(256) void k_deg(const int* __restrict__ ei,
                                             int* __restrict__ dpart) {
  __shared__ int ldeg[DEG_BIN_W];  // 50 KB
  int bin = blockIdx.x & (DEG_BINS - 1);
  int slice = blockIdx.x >> 3;
  int lo = bin * DEG_BIN_W;
  for (int i = threadIdx.x; i < DEG_BIN_W; i += 256) ldeg[i] = 0;
  __syncthreads();
  int e0 = slice * DEG_SLICE_E;
  int e1 = e0 + DEG_SLICE_E;
  for (int e = e0 + threadIdx.x; e < e1; e += 256) {
    int c = ei[N_EDGES + e] - lo;
    if ((unsigned)c < (unsigned)DEG_BIN_W) atomicAdd(&ldeg[c], 1);
  }
  __syncthreads();
  for (int i = threadIdx.x; i < DEG_BIN_W; i += 256)
    dpart[(size_t)(lo + i) * DEG_SLICES + slice] = ldeg[i];
}

// ---- scan1: deg[i] = Σ_s dpart[i][s]; dinv; per-chunk csum ----
__global__ void k_scan1(const int* __restrict__ dpart, int* __restrict__ csum,
                        float* __restrict__ dinv, int* __restrict__ deg) {
  __shared__ int lds[256];
  int b = blockIdx.x, t = threadIdx.x;
  int base = b * SCAN_CHUNK + t * 8;
  int s = 0;
#pragma unroll
  for (int k = 0; k < 8; ++k) {
    int i = base + k;
    if (i < N_NODES) {
      const int* dp = dpart + (size_t)i * DEG_SLICES;
      int d = 0;
#pragma unroll
      for (int sl = 0; sl < DEG_SLICES; ++sl) d += dp[sl];
      deg[i] = d;
      dinv[i] = rsqrtf((float)d + 1.0f);
      s += d;
    }
  }
  lds[t] = s;
  __syncthreads();
  for (int off = 128; off > 0; off >>= 1) {
    if (t < off) lds[t] += lds[t + off];
    __syncthreads();
  }
  if (t == 0) csum[b] = lds[0];
}

// ---- scan3: offsets + rewrite dpart in place to ABSOLUTE per-slice starts ----
__global__ void k_scan3(const int* __restrict__ deg, const int* __restrict__ csum,
                        int* __restrict__ offsets, int* __restrict__ dpart) {
  __shared__ int lds[256];
  __shared__ int soff;
  int b = blockIdx.x, t = threadIdx.x;
  if (t == 0) {
    int run = 0;
    for (int i = 0; i < b; ++i) run += csum[i];
    soff = run;
  }
  int base = b * SCAN_CHUNK + t * 8;
  int v[8];
  int s = 0;
#pragma unroll
  for (int k = 0; k < 8; ++k) {
    int i = base + k;
    v[k] = (i < N_NODES) ? deg[i] : 0;
    s += v[k];
  }
  lds[t] = s;
  __syncthreads();
  int total = s;
  for (int off = 1; off < 256; off <<= 1) {
    int x = (t >= off) ? lds[t - off] : 0;
    __syncthreads();
    lds[t] += x;
    __syncthreads();
  }
  int run = lds[t] - total + soff;
#pragma unroll
  for (int k = 0; k < 8; ++k) {
    int i = base + k;
    if (i < N_NODES) {
      offsets[i] = run;
      int* dp = dpart + (size_t)i * DEG_SLICES;
      int acc = run;
#pragma unroll
      for (int sl = 0; sl < DEG_SLICES; ++sl) {
        int d = dp[sl];
        dp[sl] = acc;
        acc += d;
      }
    }
    run += v[k];
  }
}

// ---- fill: LDS cursors from absolute starts -> LDS atomics only ----
__global__ __launch_bounds__(256) void k_fill(const int* __restrict__ ei,
                                              const int* __restrict__ dpart,
                                              int* __restrict__ csr_row) {
  __shared__ int cur[DEG_BIN_W];  // 50 KB
  int bin = blockIdx.x & (DEG_BINS - 1);
  int slice = blockIdx.x >> 3;
  int lo = bin * DEG_BIN_W;
  for (int i = threadIdx.x; i < DEG_BIN_W; i += 256)
    cur[i] = dpart[(size_t)(lo + i) * DEG_SLICES + slice];
  __syncthreads();
  int e0 = slice * DEG_SLICE_E;
  int e1 = e0 + DEG_SLICE_E;
  for (int e = e0 + threadIdx.x; e < e1; e += 256) {
    int c = ei[N_EDGES + e] - lo;
    if ((unsigned)c < (unsigned)DEG_BIN_W) {
      int r = ei[e];
      int p = atomicAdd(&cur[c], 1);
      csr_row[p] = r;
    }
  }
}

// ------- xw' = (x @ W1) * dinv[row], fp8-e4m3 out, MFMA 16x16x32 -------
__global__ __launch_bounds__(256, 2) void k_gemm_mfma(const float* __restrict__ x,
                                                      const float* __restrict__ W1,
                                                      const float* __restrict__ dinv,
                                                      unsigned char* __restrict__ xw8) {
  __shared__ __align__(16) unsigned short Wt[128 * 136];  // 34.8 KB
  int t = threadIdx.x;
  for (int i = t; i < 4096; i += 256) {
    float4 w4 = ((const float4*)W1)[i];
    int k = i >> 5;
    int n0 = (i & 31) * 4;
    Wt[(n0 + 0) * 136 + k] = f2bf(w4.x);
    Wt[(n0 + 1) * 136 + k] = f2bf(w4.y);
    Wt[(n0 + 2) * 136 + k] = f2bf(w4.z);
    Wt[(n0 + 3) * 136 + k] = f2bf(w4.w);
  }
  __syncthreads();

  int lane = t & 63;
  int c = lane & 15;
  int quad = lane >> 4;
  short8 b[4][8];
#pragma unroll
  for (int kt = 0; kt < 4; ++kt)
#pragma unroll
    for (int nt = 0; nt < 8; ++nt)
      b[kt][nt] = *(const short8*)&Wt[(nt * 16 + c) * 136 + kt * 32 + quad * 8];

  int wave = blockIdx.x * 4 + (t >> 6);
  for (int chunk = wave; chunk < N_CHUNKS; chunk += GEMM_BLOCKS * 4) {
    const float* xr = x + (size_t)(chunk * 16 + c) * 128 + quad * 8;
    short8 a[4];
#pragma unroll
    for (int kt = 0; kt < 4; ++kt) {
      float4 f0 = *(const float4*)(xr + kt * 32);
      float4 f1 = *(const float4*)(xr + kt * 32 + 4);
      short8 v;
      v[0] = (short)f2bf(f0.x); v[1] = (short)f2bf(f0.y);
      v[2] = (short)f2bf(f0.z); v[3] = (short)f2bf(f0.w);
      v[4] = (short)f2bf(f1.x); v[5] = (short)f2bf(f1.y);
      v[6] = (short)f2bf(f1.z); v[7] = (short)f2bf(f1.w);
      a[kt] = v;
    }
    f32x4 acc[8];
#pragma unroll
    for (int nt = 0; nt < 8; ++nt) acc[nt] = (f32x4)(0.f);
#pragma unroll
    for (int kt = 0; kt < 4; ++kt)
#pragma unroll
      for (int nt = 0; nt < 8; ++nt)
        acc[nt] = __builtin_amdgcn_mfma_f32_16x16x32_bf16(a[kt], b[kt][nt], acc[nt], 0, 0, 0);

    int rbase = chunk * 16 + quad * 4;
    float d0 = dinv[rbase + 0], d1 = dinv[rbase + 1];
    float d2 = dinv[rbase + 2], d3 = dinv[rbase + 3];
#pragma unroll
    for (int nt = 0; nt < 8; ++nt) {
      int cb = nt * 16 + c;
      float v0 = acc[nt][0] * d0, v1 = acc[nt][1] * d1;
      float v2 = acc[nt][2] * d2, v3 = acc[nt][3] * d3;
      int p01 = __builtin_amdgcn_cvt_pk_fp8_f32(v0, v1, 0, false);
      int p23 = __builtin_amdgcn_cvt_pk_fp8_f32(v2, v3, 0, false);
      xw8[(size_t)(rbase + 0) * 128 + cb] = (unsigned char)(p01 & 0xff);
      xw8[(size_t)(rbase + 1) * 128 + cb] = (unsigned char)((p01 >> 8) & 0xff);
      xw8[(size_t)(rbase + 2) * 128 + cb] = (unsigned char)(p23 & 0xff);
      xw8[(size_t)(rbase + 3) * 128 + cb] = (unsigned char)((p23 >> 8) & 0xff);
    }
  }
}

// ----- conv1: CSR gather of fp8 xw', h' = relu(dc*Σ + b1)*dc, fp8 out -----
__global__ __launch_bounds__(256) void k_conv1(const unsigned char* __restrict__ xw8,
                                               const int* __restrict__ csr_row,
                                               const int* __restrict__ offsets,
                                               const int* __restrict__ deg,
                                               const float* __restrict__ dinv,
                                               const float* __restrict__ b1,
                                               unsigned char* __restrict__ h8) {
  int lane = threadIdx.x & 63;
  int node = blockIdx.x * 4 + (threadIdx.x >> 6);
  if (node >= N_NODES) return;
  int grp = lane >> 4;
  int j = lane & 15;
  float acc[8];
#pragma unroll
  for (int k = 0; k < 8; ++k) acc[k] = 0.f;
  int st = offsets[node], cnt = deg[node];
  const uint2* rowp = (const uint2*)xw8;
#pragma unroll 4
  for (int s = 0; s <= cnt; s += 4) {
    int idx = s + grp;
    uint2 u = make_uint2(0u, 0u);
    if (idx <= cnt) {
      int r = (idx == 0) ? node : csr_row[st + idx - 1];
      u = rowp[(size_t)r * 16 + j];
    }
    f32x2 f0 = __builtin_amdgcn_cvt_pk_f32_fp8(u.x, false);
    f32x2 f1 = __builtin_amdgcn_cvt_pk_f32_fp8(u.x, true);
    f32x2 f2 = __builtin_amdgcn_cvt_pk_f32_fp8(u.y, false);
    f32x2 f3 = __builtin_amdgcn_cvt_pk_f32_fp8(u.y, true);
    acc[0] += f0[0]; acc[1] += f0[1]; acc[2] += f1[0]; acc[3] += f1[1];
    acc[4] += f2[0]; acc[5] += f2[1]; acc[6] += f3[0]; acc[7] += f3[1];
  }
#pragma unroll
  for (int k = 0; k < 8; ++k) {
    acc[k] += __shfl_xor(acc[k], 16, 64);
    acc[k] += __shfl_xor(acc[k], 32, 64);
  }
  float dc = dinv[node];
  float4 bA = *(const float4*)(b1 + j * 8);
  float4 bB = *(const float4*)(b1 + j * 8 + 4);
  if (grp == 0) {
    float o[8];
    o[0] = fmaxf(acc[0] * dc + bA.x, 0.f) * dc;
    o[1] = fmaxf(acc[1] * dc + bA.y, 0.f) * dc;
    o[2] = fmaxf(acc[2] * dc + bA.z, 0.f) * dc;
    o[3] = fmaxf(acc[3] * dc + bA.w, 0.f) * dc;
    o[4] = fmaxf(acc[4] * dc + bB.x, 0.f) * dc;
    o[5] = fmaxf(acc[5] * dc + bB.y, 0.f) * dc;
    o[6] = fmaxf(acc[6] * dc + bB.z, 0.f) * dc;
    o[7] = fmaxf(acc[7] * dc + bB.w, 0.f) * dc;
    ((uint2*)h8)[(size_t)node * 16 + j] = fp8pack8(o);
  }
}

// ----- conv2+pool fused: t[c] accumulated straight into LDS s[16][128] -----
// 1024-thr blocks x 512 grid = 32 waves/CU. After butterfly, EVERY lane holds
// the full sum for its feature block; grp0 lanes add t*dc into sacc[g].
__global__ __launch_bounds__(POOL_TPB) void k_conv2pool(const unsigned char* __restrict__ h8,
                                                        const int* __restrict__ csr_row,
                                                        const int* __restrict__ offsets,
                                                        const int* __restrict__ deg,
                                                        const float* __restrict__ dinv,
                                                        const int* __restrict__ batch,
                                                        float* __restrict__ partials) {
  __shared__ float sacc[N_GRAPHS * 128];  // 8 KB
  int t = threadIdx.x;
  for (int i = t; i < N_GRAPHS * 128; i += POOL_TPB) sacc[i] = 0.f;
  __syncthreads();
  int lane = t & 63;
  int wv = t >> 6;
  int grp = lane >> 4;
  int j = lane & 15;
  const uint2* rowp = (const uint2*)h8;
  for (int node = blockIdx.x * POOL_WPB + wv; node < N_NODES;
       node += POOL_BLOCKS * POOL_WPB) {
    float acc[8];
#pragma unroll
    for (int k = 0; k < 8; ++k) acc[k] = 0.f;
    int st = offsets[node], cnt = deg[node];
#pragma unroll 4
    for (int s = 0; s <= cnt; s += 4) {
      int idx = s + grp;
      uint2 u = make_uint2(0u, 0u);
      if (idx <= cnt) {
        int r = (idx == 0) ? node : csr_row[st + idx - 1];
        u = rowp[(size_t)r * 16 + j];
      }
      f32x2 f0 = __builtin_amdgcn_cvt_pk_f32_fp8(u.x, false);
      f32x2 f1 = __builtin_amdgcn_cvt_pk_f32_fp8(u.x, true);
      f32x2 f2 = __builtin_amdgcn_cvt_pk_f32_fp8(u.y, false);
      f32x2 f3 = __builtin_amdgcn_cvt_pk_f32_fp8(u.y, true);
      acc[0] += f0[0]; acc[1] += f0[1]; acc[2] += f1[0]; acc[3] += f1[1];
      acc[4] += f2[0]; acc[5] += f2[1]; acc[6] += f3[0]; acc[7] += f3[1];
    }
#pragma unroll
    for (int k = 0; k < 8; ++k) {
      acc[k] += __shfl_xor(acc[k], 16, 64);
      acc[k] += __shfl_xor(acc[k], 32, 64);
    }
    if (grp == 0) {
      float dc = dinv[node];
      int g = batch[node];
      float* dst = &sacc[g * 128 + j * 8];
#pragma unroll
      for (int k = 0; k < 8; ++k) atomicAdd(&dst[k], acc[k] * dc);
    }
  }
  __syncthreads();
  for (int i = t; i < N_GRAPHS * 128; i += POOL_TPB)
    partials[(size_t)blockIdx.x * (N_GRAPHS * 128) + i] = sacc[i];
}

// ----- tail: block g sums its graph's partials, dot W2, log_softmax -----
__global__ __launch_bounds__(256) void k_tail(const float* __restrict__ partials,
                                              const int* __restrict__ batch,
                                              const float* __restrict__ W2,
                                              const float* __restrict__ b2,
                                              float* __restrict__ out) {
  __shared__ float sv[128];
  __shared__ int cntsh;
  int g = blockIdx.x;
  int t = threadIdx.x;
  if (t == 0) {
    int lo = 0, hi = N_NODES;
    while (lo < hi) { int m = (lo + hi) >> 1; if (batch[m] < g) lo = m + 1; else hi = m; }
    int b0 = lo;
    lo = 0; hi = N_NODES;
    while (lo < hi) { int m = (lo + hi) >> 1; if (batch[m] < g + 1) lo = m + 1; else hi = m; }
    cntsh = lo - b0;
  }
  if (t < 128) {
    float s = 0.f;
    for (int b = 0; b < POOL_BLOCKS; ++b)
      s += partials[(size_t)b * (N_GRAPHS * 128) + g * 128 + t];
    sv[t] = s;
  }
  __syncthreads();
  if (t == 0) {
    float cnt = fmaxf((float)cntsh, 1.0f);
    float p0 = 0.f, p1 = 0.f;
    for (int f = 0; f < 128; ++f) {
      float s = sv[f];
      p0 += s * W2[f * 2 + 0];
      p1 += s * W2[f * 2 + 1];
    }
    p0 = p0 / cnt + b2[0];
    p1 = p1 / cnt + b2[1];
    float m = fmaxf(p0, p1);
    float lse = m + logf(expf(p0 - m) + expf(p1 - m));
    out[g * 2 + 0] = p0 - lse;
    out[g * 2 + 1] = p1 - lse;
  }
}

// ---------------- launch ----------------
static inline size_t align256(size_t x) { return (x + 255) & ~(size_t)255; }

extern "C" void kernel_launch(void* const* d_in, const int* in_sizes, int n_in,
                              void* d_out, int out_size, void* d_ws, size_t ws_size,
                              hipStream_t stream) {
  (void)in_sizes; (void)n_in; (void)out_size; (void)ws_size;
  const float* x  = (const float*)d_in[0];
  const int*   ei = (const int*)d_in[1];   // [2][E]
  const int*   batch = (const int*)d_in[2];
  const float* W1 = (const float*)d_in[3];
  const float* b1 = (const float*)d_in[4];
  const float* W2 = (const float*)d_in[5];
  const float* b2 = (const float*)d_in[6];
  float* out = (float*)d_out;

  char* w = (char*)d_ws;
  size_t off = 0;
  unsigned char* xw8 = (unsigned char*)(w + off); off = align256(off + (size_t)N_NODES * NHID);
  unsigned char* h8  = (unsigned char*)(w + off); off = align256(off + (size_t)N_NODES * NHID);
  int* dpart = (int*)(w + off);          off = align256(off + (size_t)N_NODES * DEG_SLICES * 4);
  int* csr_row = (int*)(w + off);        off = align256(off + (size_t)N_EDGES * 4);
  float* partials = (float*)(w + off);   off = align256(off + (size_t)POOL_BLOCKS * N_GRAPHS * 128 * 4);
  float* dinv = (float*)(w + off);       off = align256(off + (size_t)N_NODES * 4);
  int* deg = (int*)(w + off);            off = align256(off + (size_t)N_NODES * 4);
  int* offsets = (int*)(w + off);        off = align256(off + (size_t)N_NODES * 4);
  int* csum = (int*)(w + off);           off = align256(off + (size_t)NCHUNK * 4);

  k_deg<<<DEG_BINS * DEG_SLICES, 256, 0, stream>>>(ei, dpart);
  k_scan1<<<NCHUNK, 256, 0, stream>>>(dpart, csum, dinv, deg);
  k_scan3<<<NCHUNK, 256, 0, stream>>>(deg, csum, offsets, dpart);
  k_fill<<<DEG_BINS * DEG_SLICES, 256, 0, stream>>>(ei, dpart, csr_row);
  k_gemm_mfma<<<GEMM_BLOCKS, 256, 0, stream>>>(x, W1, dinv, xw8);
  k_conv1<<<(N_NODES + 3) / 4, 256, 0, stream>>>(xw8, csr_row, offsets, deg, dinv, b1, h8);
  k_conv2pool<<<POOL_BLOCKS, POOL_TPB, 0, stream>>>(h8, csr_row, offsets, deg, dinv, batch, partials);
  k_tail<<<N_GRAPHS, 256, 0, stream>>>(partials, batch, W2, b2, out);
}

// Round 11
// 415.728 us; speedup vs baseline: 1.0252x; 1.0252x over previous
//
#include <hip/hip_runtime.h>
#include <hip/hip_bf16.h>

#define N_NODES 100000
#define N_EDGES 800000
#define N_GRAPHS 16
#define NFEAT 128
#define NHID 128
#define NCLASS 2

#define SCAN_CHUNK 2048
#define NCHUNK ((N_NODES + SCAN_CHUNK - 1) / SCAN_CHUNK)  // 49

#define GEMM_BLOCKS 512
#define N_CHUNKS (N_NODES / 16)  // 6250 exact

#define DEG_BINS 8
#define DEG_SLICES 32
#define DEG_BIN_W (N_NODES / DEG_BINS)          // 12500
#define DEG_SLICE_E (N_EDGES / DEG_SLICES)      // 25000

#define P2_BLOCKS 512
#define P2_TPB 1024
#define P2_WAVES (P2_BLOCKS * (P2_TPB / 64))    // 8192
#define P2_PER ((N_NODES + P2_WAVES - 1) / P2_WAVES)  // 13

typedef unsigned int uint32;
typedef __attribute__((ext_vector_type(8))) short short8;
typedef __attribute__((ext_vector_type(4))) float f32x4;
typedef __attribute__((ext_vector_type(2))) float f32x2;

// ---- bf16 helpers ----
__device__ __forceinline__ unsigned short f2bf(float f) {
  unsigned u = __float_as_uint(f);
  unsigned r = (u + 0x7fffu + ((u >> 16) & 1u)) >> 16;
  return (unsigned short)r;
}
__device__ __forceinline__ uint32 bfpack(float a, float b) {
  return (uint32)f2bf(a) | ((uint32)f2bf(b) << 16);
}
__device__ __forceinline__ float bflo(uint32 u) { return __uint_as_float(u << 16); }
__device__ __forceinline__ float bfhi(uint32 u) { return __uint_as_float(u & 0xffff0000u); }

// -------- k_deg: LDS histogram; dpart[slice][node] written CONTIGUOUSLY --------
// R10 lesson: the transposed dpart[node][slice] writeback scattered 4B stores
// across lines shared by 16 blocks on different XCDs (~205MB amplified HBM
// writes, the hidden 130us). Contiguous per-slice rows have one writer block.
__global__ __launch_bounds__(256) void k_deg(const int* __restrict__ ei,
                                             int* __restrict__ dpart) {
  __shared__ int ldeg[DEG_BIN_W];  // 50 KB
  int bin = blockIdx.x & (DEG_BINS - 1);
  int slice = blockIdx.x >> 3;
  int lo = bin * DEG_BIN_W;
  for (int i = threadIdx.x; i < DEG_BIN_W; i += 256) ldeg[i] = 0;
  __syncthreads();
  int e0 = slice * DEG_SLICE_E;
  int e1 = e0 + DEG_SLICE_E;
  for (int e = e0 + threadIdx.x; e < e1; e += 256) {
    int c = ei[N_EDGES + e] - lo;
    if ((unsigned)c < (unsigned)DEG_BIN_W) atomicAdd(&ldeg[c], 1);
  }
  __syncthreads();
  int* dst = dpart + (size_t)slice * N_NODES + lo;
  for (int i = threadIdx.x; i < DEG_BIN_W; i += 256) dst[i] = ldeg[i];
}

// ---- scan1: deg[i] = Σ_s dpart[s][i]; dinv; per-chunk csum ----
__global__ void k_scan1(const int* __restrict__ dpart, int* __restrict__ csum,
                        float* __restrict__ dinv, int* __restrict__ deg) {
  __shared__ int lds[256];
  int b = blockIdx.x, t = threadIdx.x;
  int base = b * SCAN_CHUNK + t * 8;
  int s = 0;
#pragma unroll
  for (int k = 0; k < 8; ++k) {
    int i = base + k;
    if (i < N_NODES) {
      int d = 0;
#pragma unroll
      for (int sl = 0; sl < DEG_SLICES; ++sl) d += dpart[(size_t)sl * N_NODES + i];
      deg[i] = d;
      dinv[i] = rsqrtf((float)d + 1.0f);
      s += d;
    }
  }
  lds[t] = s;
  __syncthreads();
  for (int off = 128; off > 0; off >>= 1) {
    if (t < off) lds[t] += lds[t + off];
    __syncthreads();
  }
  if (t == 0) csum[b] = lds[0];
}

// ---- scan3: offsets + rewrite dpart in place to ABSOLUTE per-slice starts ----
// dpart[s][i] accesses: line i..i+15 of any slice touched only by this chunk's
// block (chunk = 2048 consecutive nodes) -> no cross-block line sharing.
__global__ void k_scan3(const int* __restrict__ deg, const int* __restrict__ csum,
                        int* __restrict__ offsets, int* __restrict__ dpart) {
  __shared__ int lds[256];
  __shared__ int soff;
  int b = blockIdx.x, t = threadIdx.x;
  if (t == 0) {
    int run = 0;
    for (int i = 0; i < b; ++i) run += csum[i];
    soff = run;
  }
  int base = b * SCAN_CHUNK + t * 8;
  int v[8];
  int s = 0;
#pragma unroll
  for (int k = 0; k < 8; ++k) {
    int i = base + k;
    v[k] = (i < N_NODES) ? deg[i] : 0;
    s += v[k];
  }
  lds[t] = s;
  __syncthreads();
  int total = s;
  for (int off = 1; off < 256; off <<= 1) {
    int x = (t >= off) ? lds[t - off] : 0;
    __syncthreads();
    lds[t] += x;
    __syncthreads();
  }
  int run = lds[t] - total + soff;
#pragma unroll
  for (int k = 0; k < 8; ++k) {
    int i = base + k;
    if (i < N_NODES) {
      offsets[i] = run;
      int acc = run;
#pragma unroll
      for (int sl = 0; sl < DEG_SLICES; ++sl) {
        size_t p = (size_t)sl * N_NODES + i;
        int d = dpart[p];
        dpart[p] = acc;
        acc += d;
      }
    }
    run += v[k];
  }
}

// ---- fill: LDS cursors from absolute starts -> LDS atomics only ----
__global__ __launch_bounds__(256) void k_fill(const int* __restrict__ ei,
                                              const int* __restrict__ dpart,
                                              int* __restrict__ csr_row) {
  __shared__ int cur[DEG_BIN_W];  // 50 KB
  int bin = blockIdx.x & (DEG_BINS - 1);
  int slice = blockIdx.x >> 3;
  int lo = bin * DEG_BIN_W;
  const int* src = dpart + (size_t)slice * N_NODES + lo;
  for (int i = threadIdx.x; i < DEG_BIN_W; i += 256) cur[i] = src[i];
  __syncthreads();
  int e0 = slice * DEG_SLICE_E;
  int e1 = e0 + DEG_SLICE_E;
  for (int e = e0 + threadIdx.x; e < e1; e += 256) {
    int c = ei[N_EDGES + e] - lo;
    if ((unsigned)c < (unsigned)DEG_BIN_W) {
      int r = ei[e];
      int p = atomicAdd(&cur[c], 1);
      csr_row[p] = r;
    }
  }
}

// ------- xw' = (x @ W1) * dinv[row], fp8-e4m3 out, MFMA 16x16x32 -------
__global__ __launch_bounds__(256, 2) void k_gemm_mfma(const float* __restrict__ x,
                                                      const float* __restrict__ W1,
                                                      const float* __restrict__ dinv,
                                                      unsigned char* __restrict__ xw8) {
  __shared__ __align__(16) unsigned short Wt[128 * 136];  // 34.8 KB
  int t = threadIdx.x;
  for (int i = t; i < 4096; i += 256) {
    float4 w4 = ((const float4*)W1)[i];
    int k = i >> 5;
    int n0 = (i & 31) * 4;
    Wt[(n0 + 0) * 136 + k] = f2bf(w4.x);
    Wt[(n0 + 1) * 136 + k] = f2bf(w4.y);
    Wt[(n0 + 2) * 136 + k] = f2bf(w4.z);
    Wt[(n0 + 3) * 136 + k] = f2bf(w4.w);
  }
  __syncthreads();

  int lane = t & 63;
  int c = lane & 15;
  int quad = lane >> 4;
  short8 b[4][8];
#pragma unroll
  for (int kt = 0; kt < 4; ++kt)
#pragma unroll
    for (int nt = 0; nt < 8; ++nt)
      b[kt][nt] = *(const short8*)&Wt[(nt * 16 + c) * 136 + kt * 32 + quad * 8];

  int wave = blockIdx.x * 4 + (t >> 6);
  for (int chunk = wave; chunk < N_CHUNKS; chunk += GEMM_BLOCKS * 4) {
    const float* xr = x + (size_t)(chunk * 16 + c) * 128 + quad * 8;
    short8 a[4];
#pragma unroll
    for (int kt = 0; kt < 4; ++kt) {
      float4 f0 = *(const float4*)(xr + kt * 32);
      float4 f1 = *(const float4*)(xr + kt * 32 + 4);
      short8 v;
      v[0] = (short)f2bf(f0.x); v[1] = (short)f2bf(f0.y);
      v[2] = (short)f2bf(f0.z); v[3] = (short)f2bf(f0.w);
      v[4] = (short)f2bf(f1.x); v[5] = (short)f2bf(f1.y);
      v[6] = (short)f2bf(f1.z); v[7] = (short)f2bf(f1.w);
      a[kt] = v;
    }
    f32x4 acc[8];
#pragma unroll
    for (int nt = 0; nt < 8; ++nt) acc[nt] = (f32x4)(0.f);
#pragma unroll
    for (int kt = 0; kt < 4; ++kt)
#pragma unroll
      for (int nt = 0; nt < 8; ++nt)
        acc[nt] = __builtin_amdgcn_mfma_f32_16x16x32_bf16(a[kt], b[kt][nt], acc[nt], 0, 0, 0);

    int rbase = chunk * 16 + quad * 4;
    float d0 = dinv[rbase + 0], d1 = dinv[rbase + 1];
    float d2 = dinv[rbase + 2], d3 = dinv[rbase + 3];
#pragma unroll
    for (int nt = 0; nt < 8; ++nt) {
      int cb = nt * 16 + c;
      float v0 = acc[nt][0] * d0, v1 = acc[nt][1] * d1;
      float v2 = acc[nt][2] * d2, v3 = acc[nt][3] * d3;
      int p01 = __builtin_amdgcn_cvt_pk_fp8_f32(v0, v1, 0, false);
      int p23 = __builtin_amdgcn_cvt_pk_fp8_f32(v2, v3, 0, false);
      xw8[(size_t)(rbase + 0) * 128 + cb] = (unsigned char)(p01 & 0xff);
      xw8[(size_t)(rbase + 1) * 128 + cb] = (unsigned char)((p01 >> 8) & 0xff);
      xw8[(size_t)(rbase + 2) * 128 + cb] = (unsigned char)(p23 & 0xff);
      xw8[(size_t)(rbase + 3) * 128 + cb] = (unsigned char)((p23 >> 8) & 0xff);
    }
  }
}

// ----- conv1: CSR gather of fp8 xw', h' = relu(dc*Σ + b1)*dc, bf16 out -----
__global__ __launch_bounds__(256) void k_conv1(const unsigned char* __restrict__ xw8,
                                               const int* __restrict__ csr_row,
                                               const int* __restrict__ offsets,
                                               const int* __restrict__ deg,
                                               const float* __restrict__ dinv,
                                               const float* __restrict__ b1,
                                               uint4* __restrict__ h) {
  int lane = threadIdx.x & 63;
  int node = blockIdx.x * 4 + (threadIdx.x >> 6);
  if (node >= N_NODES) return;
  int grp = lane >> 4;
  int j = lane & 15;
  float acc[8];
#pragma unroll
  for (int k = 0; k < 8; ++k) acc[k] = 0.f;
  int st = offsets[node], cnt = deg[node];
  const uint2* rowp = (const uint2*)xw8;
#pragma unroll 4
  for (int s = 0; s <= cnt; s += 4) {
    int idx = s + grp;
    uint2 u = make_uint2(0u, 0u);
    if (idx <= cnt) {
      int r = (idx == 0) ? node : csr_row[st + idx - 1];
      u = rowp[(size_t)r * 16 + j];
    }
    f32x2 f0 = __builtin_amdgcn_cvt_pk_f32_fp8(u.x, false);
    f32x2 f1 = __builtin_amdgcn_cvt_pk_f32_fp8(u.x, true);
    f32x2 f2 = __builtin_amdgcn_cvt_pk_f32_fp8(u.y, false);
    f32x2 f3 = __builtin_amdgcn_cvt_pk_f32_fp8(u.y, true);
    acc[0] += f0[0]; acc[1] += f0[1]; acc[2] += f1[0]; acc[3] += f1[1];
    acc[4] += f2[0]; acc[5] += f2[1]; acc[6] += f3[0]; acc[7] += f3[1];
  }
#pragma unroll
  for (int k = 0; k < 8; ++k) {
    acc[k] += __shfl_xor(acc[k], 16, 64);
    acc[k] += __shfl_xor(acc[k], 32, 64);
  }
  float dc = dinv[node];
  float4 bA = *(const float4*)(b1 + j * 8);
  float4 bB = *(const float4*)(b1 + j * 8 + 4);
  if (grp == 0) {
    float o0 = fmaxf(acc[0] * dc + bA.x, 0.f) * dc;
    float o1 = fmaxf(acc[1] * dc + bA.y, 0.f) * dc;
    float o2 = fmaxf(acc[2] * dc + bA.z, 0.f) * dc;
    float o3 = fmaxf(acc[3] * dc + bA.w, 0.f) * dc;
    float o4 = fmaxf(acc[4] * dc + bB.x, 0.f) * dc;
    float o5 = fmaxf(acc[5] * dc + bB.y, 0.f) * dc;
    float o6 = fmaxf(acc[6] * dc + bB.z, 0.f) * dc;
    float o7 = fmaxf(acc[7] * dc + bB.w, 0.f) * dc;
    uint4 w;
    w.x = bfpack(o0, o1); w.y = bfpack(o2, o3);
    w.z = bfpack(o4, o5); w.w = bfpack(o6, o7);
    h[(size_t)node * 16 + j] = w;
  }
}

// ----- conv2+pool v2: contiguous node runs per wave, register pool acc -----
// batch is sorted, so a wave's 13-node range crosses ~0-1 graph boundaries:
// pacc flushes to LDS only on boundary (~2 flushes/wave, not per-node). This
// deletes R10's 12.8M contended per-node LDS atomics.
__global__ __launch_bounds__(P2_TPB) void k_conv2pool(const uint4* __restrict__ h,
                                                      const int* __restrict__ csr_row,
                                                      const int* __restrict__ offsets,
                                                      const int* __restrict__ deg,
                                                      const float* __restrict__ dinv,
                                                      const int* __restrict__ batch,
                                                      float* __restrict__ partials) {
  __shared__ float sacc[N_GRAPHS * 128];  // 8 KB
  int t = threadIdx.x;
  for (int i = t; i < N_GRAPHS * 128; i += P2_TPB) sacc[i] = 0.f;
  __syncthreads();
  int lane = t & 63;
  int grp = lane >> 4;
  int j = lane & 15;
  int w = blockIdx.x * (P2_TPB / 64) + (t >> 6);
  int n0 = w * P2_PER;
  int n1 = min(n0 + P2_PER, N_NODES);
  float pacc[8];
#pragma unroll
  for (int k = 0; k < 8; ++k) pacc[k] = 0.f;
  int gcur = -1;
  for (int node = n0; node < n1; ++node) {
    float acc[8];
#pragma unroll
    for (int k = 0; k < 8; ++k) acc[k] = 0.f;
    int st = offsets[node], cnt = deg[node];
#pragma unroll 4
    for (int s = 0; s <= cnt; s += 4) {
      int idx = s + grp;
      uint4 u = make_uint4(0u, 0u, 0u, 0u);
      if (idx <= cnt) {
        int r = (idx == 0) ? node : csr_row[st + idx - 1];
        u = h[(size_t)r * 16 + j];
      }
      acc[0] += bflo(u.x); acc[1] += bfhi(u.x);
      acc[2] += bflo(u.y); acc[3] += bfhi(u.y);
      acc[4] += bflo(u.z); acc[5] += bfhi(u.z);
      acc[6] += bflo(u.w); acc[7] += bfhi(u.w);
    }
#pragma unroll
    for (int k = 0; k < 8; ++k) {
      acc[k] += __shfl_xor(acc[k], 16, 64);
      acc[k] += __shfl_xor(acc[k], 32, 64);
    }
    int g = batch[node];  // wave-uniform branch (node uniform)
    if (g != gcur) {
      if (gcur >= 0 && grp == 0) {
        float* dst = &sacc[gcur * 128 + j * 8];
#pragma unroll
        for (int k = 0; k < 8; ++k) atomicAdd(&dst[k], pacc[k]);
      }
#pragma unroll
      for (int k = 0; k < 8; ++k) pacc[k] = 0.f;
      gcur = g;
    }
    float dc = dinv[node];
#pragma unroll
    for (int k = 0; k < 8; ++k) pacc[k] += acc[k] * dc;
  }
  if (gcur >= 0 && grp == 0) {
    float* dst = &sacc[gcur * 128 + j * 8];
#pragma unroll
    for (int k = 0; k < 8; ++k) atomicAdd(&dst[k], pacc[k]);
  }
  __syncthreads();
  for (int i = t; i < N_GRAPHS * 128; i += P2_TPB)
    partials[(size_t)blockIdx.x * (N_GRAPHS * 128) + i] = sacc[i];
}

// ----- tail: block g sums its graph's partials, dot W2, log_softmax -----
__global__ __launch_bounds__(256) void k_tail(const float* __restrict__ partials,
                                              const int* __restrict__ batch,
                                              const float* __restrict__ W2,
                                              const float* __restrict__ b2,
                                              float* __restrict__ out) {
  __shared__ float sv[128];
  __shared__ int cntsh;
  int g = blockIdx.x;
  int t = threadIdx.x;
  if (t == 0) {
    int lo = 0, hi = N_NODES;
    while (lo < hi) { int m = (lo + hi) >> 1; if (batch[m] < g) lo = m + 1; else hi = m; }
    int b0 = lo;
    lo = 0; hi = N_NODES;
    while (lo < hi) { int m = (lo + hi) >> 1; if (batch[m] < g + 1) lo = m + 1; else hi = m; }
    cntsh = lo - b0;
  }
  if (t < 128) {
    float s = 0.f;
    for (int b = 0; b < P2_BLOCKS; ++b)
      s += partials[(size_t)b * (N_GRAPHS * 128) + g * 128 + t];
    sv[t] = s;
  }
  __syncthreads();
  if (t == 0) {
    float cnt = fmaxf((float)cntsh, 1.0f);
    float p0 = 0.f, p1 = 0.f;
    for (int f = 0; f < 128; ++f) {
      float s = sv[f];
      p0 += s * W2[f * 2 + 0];
      p1 += s * W2[f * 2 + 1];
    }
    p0 = p0 / cnt + b2[0];
    p1 = p1 / cnt + b2[1];
    float m = fmaxf(p0, p1);
    float lse = m + logf(expf(p0 - m) + expf(p1 - m));
    out[g * 2 + 0] = p0 - lse;
    out[g * 2 + 1] = p1 - lse;
  }
}

// ---------------- launch ----------------
static inline size_t align256(size_t x) { return (x + 255) & ~(size_t)255; }

extern "C" void kernel_launch(void* const* d_in, const int* in_sizes, int n_in,
                              void* d_out, int out_size, void* d_ws, size_t ws_size,
                              hipStream_t stream) {
  (void)in_sizes; (void)n_in; (void)out_size; (void)ws_size;
  const float* x  = (const float*)d_in[0];
  const int*   ei = (const int*)d_in[1];   // [2][E]
  const int*   batch = (const int*)d_in[2];
  const float* W1 = (const float*)d_in[3];
  const float* b1 = (const float*)d_in[4];
  const float* W2 = (const float*)d_in[5];
  const float* b2 = (const float*)d_in[6];
  float* out = (float*)d_out;

  char* w = (char*)d_ws;
  size_t off = 0;
  unsigned char* xw8 = (unsigned char*)(w + off); off = align256(off + (size_t)N_NODES * NHID);
  uint4* h = (uint4*)(w + off);          off = align256(off + (size_t)N_NODES * NHID * 2);
  int* dpart = (int*)(w + off);          off = align256(off + (size_t)DEG_SLICES * N_NODES * 4);
  int* csr_row = (int*)(w + off);        off = align256(off + (size_t)N_EDGES * 4);
  float* partials = (float*)(w + off);   off = align256(off + (size_t)P2_BLOCKS * N_GRAPHS * 128 * 4);
  float* dinv = (float*)(w + off);       off = align256(off + (size_t)N_NODES * 4);
  int* deg = (int*)(w + off);            off = align256(off + (size_t)N_NODES * 4);
  int* offsets = (int*)(w + off);        off = align256(off + (size_t)N_NODES * 4);
  int* csum = (int*)(w + off);           off = align256(off + (size_t)NCHUNK * 4);

  k_deg<<<DEG_BINS * DEG_SLICES, 256, 0, stream>>>(ei, dpart);
  k_scan1<<<NCHUNK, 256, 0, stream>>>(dpart, csum, dinv, deg);
  k_scan3<<<NCHUNK, 256, 0, stream>>>(deg, csum, offsets, dpart);
  k_fill<<<DEG_BINS * DEG_SLICES, 256, 0, stream>>>(ei, dpart, csr_row);
  k_gemm_mfma<<<GEMM_BLOCKS, 256, 0, stream>>>(x, W1, dinv, xw8);
  k_conv1<<<(N_NODES + 3) / 4, 256, 0, stream>>>(xw8, csr_row, offsets, deg, dinv, b1, h);
  k_conv2pool<<<P2_BLOCKS, P2_TPB, 0, stream>>>(h, csr_row, offsets, deg, dinv, batch, partials);
  k_tail<<<N_GRAPHS, 256, 0, stream>>>(partials, batch, W2, b2, out);
}

// Round 12
// 317.607 us; speedup vs baseline: 1.3419x; 1.3089x over previous
//
#include <hip/hip_runtime.h>
#include <hip/hip_bf16.h>

#define N_NODES 100000
#define N_EDGES 800000
#define N_GRAPHS 16
#define NFEAT 128
#define NHID 128
#define NCLASS 2

#define SCAN_CHUNK 2048
#define NCHUNK ((N_NODES + SCAN_CHUNK - 1) / SCAN_CHUNK)  // 49

#define GEMM_BLOCKS 512
#define N_CHUNKS (N_NODES / 16)  // 6250 exact

#define FILL_BINS 8
#define FILL_SLICES 128
#define FILL_BIN_W (N_NODES / FILL_BINS)        // 12500
#define FILL_SLICE_E (N_EDGES / FILL_SLICES)    // 6250

#define P2_BLOCKS 512
#define P2_TPB 1024
#define P2_WAVES (P2_BLOCKS * (P2_TPB / 64))    // 8192
#define P2_PER ((N_NODES + P2_WAVES - 1) / P2_WAVES)  // 13

typedef unsigned int uint32;
typedef __attribute__((ext_vector_type(8))) short short8;
typedef __attribute__((ext_vector_type(4))) float f32x4;
typedef __attribute__((ext_vector_type(2))) float f32x2;

// ---- bf16 helpers ----
__device__ __forceinline__ unsigned short f2bf(float f) {
  unsigned u = __float_as_uint(f);
  unsigned r = (u + 0x7fffu + ((u >> 16) & 1u)) >> 16;
  return (unsigned short)r;
}
__device__ __forceinline__ uint32 bfpack(float a, float b) {
  return (uint32)f2bf(a) | ((uint32)f2bf(b) << 16);
}
__device__ __forceinline__ float bflo(uint32 u) { return __uint_as_float(u << 16); }
__device__ __forceinline__ float bfhi(uint32 u) { return __uint_as_float(u & 0xffff0000u); }

// ---- k_deg: plain global int atomics (R7-proven; binning/LDS variants both
// regressed: R8 binned = fewer blocks + 8x re-read; R11 LDS hist = occupancy cap) ----
__global__ void k_deg(const int* __restrict__ ei, int* __restrict__ deg) {
  int e = blockIdx.x * blockDim.x + threadIdx.x;
  if (e < N_EDGES) atomicAdd(&deg[ei[N_EDGES + e]], 1);
}

// ---- scan1: per-chunk sums + dinv ----
__global__ void k_scan1(const int* __restrict__ deg, int* __restrict__ csum,
                        float* __restrict__ dinv) {
  __shared__ int lds[256];
  int b = blockIdx.x, t = threadIdx.x;
  int base = b * SCAN_CHUNK + t * 8;
  int s = 0;
#pragma unroll
  for (int k = 0; k < 8; ++k) {
    int i = base + k;
    int d = (i < N_NODES) ? deg[i] : 0;
    if (i < N_NODES) dinv[i] = rsqrtf((float)d + 1.0f);
    s += d;
  }
  lds[t] = s;
  __syncthreads();
  for (int off = 128; off > 0; off >>= 1) {
    if (t < off) lds[t] += lds[t + off];
    __syncthreads();
  }
  if (t == 0) csum[b] = lds[0];
}

// ---- scan3: offsets + cursor (cursor starts at offsets; fill atomics on it) ----
__global__ void k_scan3(const int* __restrict__ deg, const int* __restrict__ csum,
                        int* __restrict__ offsets, int* __restrict__ cursor) {
  __shared__ int lds[256];
  __shared__ int soff;
  int b = blockIdx.x, t = threadIdx.x;
  if (t == 0) {
    int run = 0;
    for (int i = 0; i < b; ++i) run += csum[i];
    soff = run;
  }
  int base = b * SCAN_CHUNK + t * 8;
  int v[8];
  int s = 0;
#pragma unroll
  for (int k = 0; k < 8; ++k) {
    int i = base + k;
    v[k] = (i < N_NODES) ? deg[i] : 0;
    s += v[k];
  }
  lds[t] = s;
  __syncthreads();
  int total = s;
  for (int off = 1; off < 256; off <<= 1) {
    int x = (t >= off) ? lds[t - off] : 0;
    __syncthreads();
    lds[t] += x;
    __syncthreads();
  }
  int run = lds[t] - total + soff;
#pragma unroll
  for (int k = 0; k < 8; ++k) {
    int i = base + k;
    if (i < N_NODES) { offsets[i] = run; cursor[i] = run; }
    run += v[k];
  }
}

// ---- fill: XCD-binned, GLOBAL cursor atomics (R7-proven: binning makes each
// csr_row/cursor line single-XCD-writer, killing the 18x write amplification;
// R11's LDS-cursor variant regressed on occupancy + bank conflicts) ----
__global__ __launch_bounds__(256) void k_fill(const int* __restrict__ ei,
                                              int* __restrict__ cursor,
                                              int* __restrict__ csr_row) {
  int bin = blockIdx.x & (FILL_BINS - 1);
  int slice = blockIdx.x >> 3;
  int lo = bin * FILL_BIN_W;
  int hi = lo + FILL_BIN_W;
  int e0 = slice * FILL_SLICE_E;
  int e1 = e0 + FILL_SLICE_E;
  for (int e = e0 + threadIdx.x; e < e1; e += 256) {
    int c = ei[N_EDGES + e];
    if (c >= lo && c < hi) {
      int r = ei[e];
      int p = atomicAdd(&cursor[c], 1);
      csr_row[p] = r;
    }
  }
}

// ------- xw' = (x @ W1) * dinv[row], fp8-e4m3 out, MFMA 16x16x32 -------
__global__ __launch_bounds__(256, 2) void k_gemm_mfma(const float* __restrict__ x,
                                                      const float* __restrict__ W1,
                                                      const float* __restrict__ dinv,
                                                      unsigned char* __restrict__ xw8) {
  __shared__ __align__(16) unsigned short Wt[128 * 136];  // 34.8 KB
  int t = threadIdx.x;
  for (int i = t; i < 4096; i += 256) {
    float4 w4 = ((const float4*)W1)[i];
    int k = i >> 5;
    int n0 = (i & 31) * 4;
    Wt[(n0 + 0) * 136 + k] = f2bf(w4.x);
    Wt[(n0 + 1) * 136 + k] = f2bf(w4.y);
    Wt[(n0 + 2) * 136 + k] = f2bf(w4.z);
    Wt[(n0 + 3) * 136 + k] = f2bf(w4.w);
  }
  __syncthreads();

  int lane = t & 63;
  int c = lane & 15;
  int quad = lane >> 4;
  short8 b[4][8];
#pragma unroll
  for (int kt = 0; kt < 4; ++kt)
#pragma unroll
    for (int nt = 0; nt < 8; ++nt)
      b[kt][nt] = *(const short8*)&Wt[(nt * 16 + c) * 136 + kt * 32 + quad * 8];

  int wave = blockIdx.x * 4 + (t >> 6);
  for (int chunk = wave; chunk < N_CHUNKS; chunk += GEMM_BLOCKS * 4) {
    const float* xr = x + (size_t)(chunk * 16 + c) * 128 + quad * 8;
    short8 a[4];
#pragma unroll
    for (int kt = 0; kt < 4; ++kt) {
      float4 f0 = *(const float4*)(xr + kt * 32);
      float4 f1 = *(const float4*)(xr + kt * 32 + 4);
      short8 v;
      v[0] = (short)f2bf(f0.x); v[1] = (short)f2bf(f0.y);
      v[2] = (short)f2bf(f0.z); v[3] = (short)f2bf(f0.w);
      v[4] = (short)f2bf(f1.x); v[5] = (short)f2bf(f1.y);
      v[6] = (short)f2bf(f1.z); v[7] = (short)f2bf(f1.w);
      a[kt] = v;
    }
    f32x4 acc[8];
#pragma unroll
    for (int nt = 0; nt < 8; ++nt) acc[nt] = (f32x4)(0.f);
#pragma unroll
    for (int kt = 0; kt < 4; ++kt)
#pragma unroll
      for (int nt = 0; nt < 8; ++nt)
        acc[nt] = __builtin_amdgcn_mfma_f32_16x16x32_bf16(a[kt], b[kt][nt], acc[nt], 0, 0, 0);

    int rbase = chunk * 16 + quad * 4;
    float d0 = dinv[rbase + 0], d1 = dinv[rbase + 1];
    float d2 = dinv[rbase + 2], d3 = dinv[rbase + 3];
#pragma unroll
    for (int nt = 0; nt < 8; ++nt) {
      int cb = nt * 16 + c;
      float v0 = acc[nt][0] * d0, v1 = acc[nt][1] * d1;
      float v2 = acc[nt][2] * d2, v3 = acc[nt][3] * d3;
      int p01 = __builtin_amdgcn_cvt_pk_fp8_f32(v0, v1, 0, false);
      int p23 = __builtin_amdgcn_cvt_pk_fp8_f32(v2, v3, 0, false);
      xw8[(size_t)(rbase + 0) * 128 + cb] = (unsigned char)(p01 & 0xff);
      xw8[(size_t)(rbase + 1) * 128 + cb] = (unsigned char)((p01 >> 8) & 0xff);
      xw8[(size_t)(rbase + 2) * 128 + cb] = (unsigned char)(p23 & 0xff);
      xw8[(size_t)(rbase + 3) * 128 + cb] = (unsigned char)((p23 >> 8) & 0xff);
    }
  }
}

// ----- conv1: CSR gather of fp8 xw', h' = relu(dc*Σ + b1)*dc, bf16 out -----
__global__ __launch_bounds__(256) void k_conv1(const unsigned char* __restrict__ xw8,
                                               const int* __restrict__ csr_row,
                                               const int* __restrict__ offsets,
                                               const int* __restrict__ deg,
                                               const float* __restrict__ dinv,
                                               const float* __restrict__ b1,
                                               uint4* __restrict__ h) {
  int lane = threadIdx.x & 63;
  int node = blockIdx.x * 4 + (threadIdx.x >> 6);
  if (node >= N_NODES) return;
  int grp = lane >> 4;
  int j = lane & 15;
  float acc[8];
#pragma unroll
  for (int k = 0; k < 8; ++k) acc[k] = 0.f;
  int st = offsets[node], cnt = deg[node];
  const uint2* rowp = (const uint2*)xw8;
#pragma unroll 4
  for (int s = 0; s <= cnt; s += 4) {
    int idx = s + grp;
    uint2 u = make_uint2(0u, 0u);
    if (idx <= cnt) {
      int r = (idx == 0) ? node : csr_row[st + idx - 1];
      u = rowp[(size_t)r * 16 + j];
    }
    f32x2 f0 = __builtin_amdgcn_cvt_pk_f32_fp8(u.x, false);
    f32x2 f1 = __builtin_amdgcn_cvt_pk_f32_fp8(u.x, true);
    f32x2 f2 = __builtin_amdgcn_cvt_pk_f32_fp8(u.y, false);
    f32x2 f3 = __builtin_amdgcn_cvt_pk_f32_fp8(u.y, true);
    acc[0] += f0[0]; acc[1] += f0[1]; acc[2] += f1[0]; acc[3] += f1[1];
    acc[4] += f2[0]; acc[5] += f2[1]; acc[6] += f3[0]; acc[7] += f3[1];
  }
#pragma unroll
  for (int k = 0; k < 8; ++k) {
    acc[k] += __shfl_xor(acc[k], 16, 64);
    acc[k] += __shfl_xor(acc[k], 32, 64);
  }
  float dc = dinv[node];
  float4 bA = *(const float4*)(b1 + j * 8);
  float4 bB = *(const float4*)(b1 + j * 8 + 4);
  if (grp == 0) {
    float o0 = fmaxf(acc[0] * dc + bA.x, 0.f) * dc;
    float o1 = fmaxf(acc[1] * dc + bA.y, 0.f) * dc;
    float o2 = fmaxf(acc[2] * dc + bA.z, 0.f) * dc;
    float o3 = fmaxf(acc[3] * dc + bA.w, 0.f) * dc;
    float o4 = fmaxf(acc[4] * dc + bB.x, 0.f) * dc;
    float o5 = fmaxf(acc[5] * dc + bB.y, 0.f) * dc;
    float o6 = fmaxf(acc[6] * dc + bB.z, 0.f) * dc;
    float o7 = fmaxf(acc[7] * dc + bB.w, 0.f) * dc;
    uint4 w;
    w.x = bfpack(o0, o1); w.y = bfpack(o2, o3);
    w.z = bfpack(o4, o5); w.w = bfpack(o6, o7);
    h[(size_t)node * 16 + j] = w;
  }
}

// ----- conv2+pool: contiguous node runs per wave, register pool acc (R11) -----
__global__ __launch_bounds__(P2_TPB) void k_conv2pool(const uint4* __restrict__ h,
                                                      const int* __restrict__ csr_row,
                                                      const int* __restrict__ offsets,
                                                      const int* __restrict__ deg,
                                                      const float* __restrict__ dinv,
                                                      const int* __restrict__ batch,
                                                      float* __restrict__ partials) {
  __shared__ float sacc[N_GRAPHS * 128];  // 8 KB
  int t = threadIdx.x;
  for (int i = t; i < N_GRAPHS * 128; i += P2_TPB) sacc[i] = 0.f;
  __syncthreads();
  int lane = t & 63;
  int grp = lane >> 4;
  int j = lane & 15;
  int w = blockIdx.x * (P2_TPB / 64) + (t >> 6);
  int n0 = w * P2_PER;
  int n1 = min(n0 + P2_PER, N_NODES);
  float pacc[8];
#pragma unroll
  for (int k = 0; k < 8; ++k) pacc[k] = 0.f;
  int gcur = -1;
  for (int node = n0; node < n1; ++node) {
    float acc[8];
#pragma unroll
    for (int k = 0; k < 8; ++k) acc[k] = 0.f;
    int st = offsets[node], cnt = deg[node];
#pragma unroll 4
    for (int s = 0; s <= cnt; s += 4) {
      int idx = s + grp;
      uint4 u = make_uint4(0u, 0u, 0u, 0u);
      if (idx <= cnt) {
        int r = (idx == 0) ? node : csr_row[st + idx - 1];
        u = h[(size_t)r * 16 + j];
      }
      acc[0] += bflo(u.x); acc[1] += bfhi(u.x);
      acc[2] += bflo(u.y); acc[3] += bfhi(u.y);
      acc[4] += bflo(u.z); acc[5] += bfhi(u.z);
      acc[6] += bflo(u.w); acc[7] += bfhi(u.w);
    }
#pragma unroll
    for (int k = 0; k < 8; ++k) {
      acc[k] += __shfl_xor(acc[k], 16, 64);
      acc[k] += __shfl_xor(acc[k], 32, 64);
    }
    int g = batch[node];  // wave-uniform
    if (g != gcur) {
      if (gcur >= 0 && grp == 0) {
        float* dst = &sacc[gcur * 128 + j * 8];
#pragma unroll
        for (int k = 0; k < 8; ++k) atomicAdd(&dst[k], pacc[k]);
      }
#pragma unroll
      for (int k = 0; k < 8; ++k) pacc[k] = 0.f;
      gcur = g;
    }
    float dc = dinv[node];
#pragma unroll
    for (int k = 0; k < 8; ++k) pacc[k] += acc[k] * dc;
  }
  if (gcur >= 0 && grp == 0) {
    float* dst = &sacc[gcur * 128 + j * 8];
#pragma unroll
    for (int k = 0; k < 8; ++k) atomicAdd(&dst[k], pacc[k]);
  }
  __syncthreads();
  for (int i = t; i < N_GRAPHS * 128; i += P2_TPB)
    partials[(size_t)blockIdx.x * (N_GRAPHS * 128) + i] = sacc[i];
}

// ----- tail: block g sums its graph's partials, dot W2, log_softmax -----
__global__ __launch_bounds__(256) void k_tail(const float* __restrict__ partials,
                                              const int* __restrict__ batch,
                                              const float* __restrict__ W2,
                                              const float* __restrict__ b2,
                                              float* __restrict__ out) {
  __shared__ float sv[128];
  __shared__ int cntsh;
  int g = blockIdx.x;
  int t = threadIdx.x;
  if (t == 0) {
    int lo = 0, hi = N_NODES;
    while (lo < hi) { int m = (lo + hi) >> 1; if (batch[m] < g) lo = m + 1; else hi = m; }
    int b0 = lo;
    lo = 0; hi = N_NODES;
    while (lo < hi) { int m = (lo + hi) >> 1; if (batch[m] < g + 1) lo = m + 1; else hi = m; }
    cntsh = lo - b0;
  }
  if (t < 128) {
    float s = 0.f;
    for (int b = 0; b < P2_BLOCKS; ++b)
      s += partials[(size_t)b * (N_GRAPHS * 128) + g * 128 + t];
    sv[t] = s;
  }
  __syncthreads();
  if (t == 0) {
    float cnt = fmaxf((float)cntsh, 1.0f);
    float p0 = 0.f, p1 = 0.f;
    for (int f = 0; f < 128; ++f) {
      float s = sv[f];
      p0 += s * W2[f * 2 + 0];
      p1 += s * W2[f * 2 + 1];
    }
    p0 = p0 / cnt + b2[0];
    p1 = p1 / cnt + b2[1];
    float m = fmaxf(p0, p1);
    float lse = m + logf(expf(p0 - m) + expf(p1 - m));
    out[g * 2 + 0] = p0 - lse;
    out[g * 2 + 1] = p1 - lse;
  }
}

// ---------------- launch ----------------
static inline size_t align256(size_t x) { return (x + 255) & ~(size_t)255; }

extern "C" void kernel_launch(void* const* d_in, const int* in_sizes, int n_in,
                              void* d_out, int out_size, void* d_ws, size_t ws_size,
                              hipStream_t stream) {
  (void)in_sizes; (void)n_in; (void)out_size; (void)ws_size;
  const float* x  = (const float*)d_in[0];
  const int*   ei = (const int*)d_in[1];   // [2][E]
  const int*   batch = (const int*)d_in[2];
  const float* W1 = (const float*)d_in[3];
  const float* b1 = (const float*)d_in[4];
  const float* W2 = (const float*)d_in[5];
  const float* b2 = (const float*)d_in[6];
  float* out = (float*)d_out;

  char* w = (char*)d_ws;
  size_t off = 0;
  unsigned char* xw8 = (unsigned char*)(w + off); off = align256(off + (size_t)N_NODES * NHID);
  uint4* h = (uint4*)(w + off);          off = align256(off + (size_t)N_NODES * NHID * 2);
  int* csr_row = (int*)(w + off);        off = align256(off + (size_t)N_EDGES * 4);
  float* partials = (float*)(w + off);   off = align256(off + (size_t)P2_BLOCKS * N_GRAPHS * 128 * 4);
  float* dinv = (float*)(w + off);       off = align256(off + (size_t)N_NODES * 4);
  int* deg = (int*)(w + off);            off = align256(off + (size_t)N_NODES * 4);
  int* cursor = (int*)(w + off);         off = align256(off + (size_t)N_NODES * 4);
  int* offsets = (int*)(w + off);        off = align256(off + (size_t)N_NODES * 4);
  int* csum = (int*)(w + off);           off = align256(off + (size_t)NCHUNK * 4);

  hipMemsetAsync(deg, 0, (size_t)N_NODES * 4, stream);
  k_deg<<<(N_EDGES + 255) / 256, 256, 0, stream>>>(ei, deg);
  k_scan1<<<NCHUNK, 256, 0, stream>>>(deg, csum, dinv);
  k_scan3<<<NCHUNK, 256, 0, stream>>>(deg, csum, offsets, cursor);
  k_fill<<<FILL_BINS * FILL_SLICES, 256, 0, stream>>>(ei, cursor, csr_row);
  k_gemm_mfma<<<GEMM_BLOCKS, 256, 0, stream>>>(x, W1, dinv, xw8);
  k_conv1<<<(N_NODES + 3) / 4, 256, 0, stream>>>(xw8, csr_row, offsets, deg, dinv, b1, h);
  k_conv2pool<<<P2_BLOCKS, P2_TPB, 0, stream>>>(h, csr_row, offsets, deg, dinv, batch, partials);
  k_tail<<<N_GRAPHS, 256, 0, stream>>>(partials, batch, W2, b2, out);
}